// Round 6
// baseline (233.341 us; speedup 1.0000x reference)
//
#include <hip/hip_runtime.h>
#include <math.h>

#define N_SRC 200000
#define N_DST 40000
#define N_EDGES 8000000
#define N_LAYERS 6
#define N_OUT (N_DST * 12)

#define EBLK 512          // edge blocks == partial-hist chunks
#define ETPB 512          // threads per edge block (8 waves; 4 blocks/CU via 40KB LDS)

typedef int vint4 __attribute__((ext_vector_type(4)));

// Device-global scratch (fully rewritten every call).
__device__ float4 g_psrc[N_SRC];                    // (energy, eta, phi, layer-bits)
__device__ float2 g_pdst[N_DST];                    // (eta, phi)
__device__ unsigned int g_partial[EBLK][N_DST / 4]; // u8 bins packed in u32 (20.5 MB)

// Pack gather tables AND zero the output accumulators (one dispatch).
__global__ __launch_bounds__(256) void pack_kernel(
        const float* __restrict__ energy, const int* __restrict__ layer,
        const float* __restrict__ eta_s, const float* __restrict__ phi_s,
        const float* __restrict__ eta_d, const float* __restrict__ phi_d,
        float* __restrict__ out) {
    int i = blockIdx.x * blockDim.x + threadIdx.x;
    if (i < N_SRC) {
        float4 p;
        p.x = energy[i];
        p.y = eta_s[i];
        p.z = phi_s[i];
        p.w = __int_as_float(layer[i]);
        g_psrc[i] = p;
    }
    if (i < N_DST) g_pdst[i] = make_float2(eta_d[i], phi_d[i]);
    if (i < N_OUT) out[i] = 0.0f;
}

__device__ __forceinline__ void edge_compute(unsigned int* __restrict__ bins,
                                             int s, int d,
                                             float* __restrict__ out) {
    // degree: LDS u8-packed histogram (always)
    atomicAdd(&bins[d >> 2], 1u << ((d & 3) * 8));

    float4 p = g_psrc[s];
    float2 q = g_pdst[d];

    const float pif   = 3.14159265358979323846f;
    const float twopi = 6.28318530717958647692f;
    float deta = p.y - q.x;
    float dphi = p.z - q.y;
    dphi = (dphi >  pif) ? dphi - twopi : dphi;
    dphi = (dphi < -pif) ? dphi + twopi : dphi;
    float dr = sqrtf(deta * deta + dphi * dphi);
    if (dr < 0.4f) {
        int   l = __float_as_int(p.w);
        float e = p.x;
        float* base = out + (size_t)d * 12;
        atomicAdd(base + l,     e);
        atomicAdd(base + 6 + l, e * e);
    }
}

// Fused: degree histogram (LDS, u8-packed) + dR cut + sum/sq atomics.
// 512 blocks x 512 threads, 40KB LDS -> 4 blocks/CU = 32 waves/CU.
// Per-block edges <= 16384 over 40000 bins: u8 counters safe.
__global__ __launch_bounds__(ETPB, 8) void edge_kernel(
        const vint4* __restrict__ src4, const vint4* __restrict__ dst4,
        float* __restrict__ out) {
    __shared__ unsigned int bins[N_DST / 4];  // 40 KB

    for (int i = threadIdx.x; i < N_DST / 4; i += ETPB) bins[i] = 0u;
    __syncthreads();

    const int nvec = N_EDGES / 4;
    for (int v = blockIdx.x * ETPB + threadIdx.x; v < nvec; v += EBLK * ETPB) {
        vint4 s4 = __builtin_nontemporal_load(src4 + v);
        vint4 d4 = __builtin_nontemporal_load(dst4 + v);
        edge_compute(bins, s4.x, d4.x, out);
        edge_compute(bins, s4.y, d4.y, out);
        edge_compute(bins, s4.z, d4.z, out);
        edge_compute(bins, s4.w, d4.w, out);
    }
    __syncthreads();

    unsigned int* po = &g_partial[blockIdx.x][0];
    for (int i = threadIdx.x; i < N_DST / 4; i += ETPB)
        __builtin_nontemporal_store(bins[i], po + i);
}

__device__ __forceinline__ void finalize_one(float* __restrict__ out, int d, float dg) {
    float mean_den = fmaxf(dg, 1.0f);
    float var_den  = fmaxf(dg - 1.0f, 1.0f);
    bool  valid    = dg > 1.0f;
    float* base = out + (size_t)d * 12;
#pragma unroll
    for (int l = 0; l < N_LAYERS; ++l) {
        float s = base[l];
        float q = base[6 + l];
        float mean = s / mean_den;
        float t = dg * mean;
        t = t * mean;
        float var = (q - t) / var_den;
        var = fmaxf(var, 0.0f);
        float sd = (var > 0.0f) ? sqrtf(var) : 0.0f;
        if (!valid) sd = 0.0f;
        base[6 + l] = sd;
    }
}

// Fused partial-hist reduction + std finalize. One thread per u32 word
// (4 dst bins): 10000 threads, coalesced reads of g_partial (20.5 MB).
__global__ __launch_bounds__(256) void finalize_kernel(float* __restrict__ out) {
    int t = blockIdx.x * blockDim.x + threadIdx.x;
    if (t >= N_DST / 4) return;
    unsigned int c0 = 0, c1 = 0, c2 = 0, c3 = 0;
#pragma unroll 8
    for (int p = 0; p < EBLK; ++p) {
        unsigned int w = g_partial[p][t];
        c0 += w & 255u;
        c1 += (w >> 8) & 255u;
        c2 += (w >> 16) & 255u;
        c3 += (w >> 24);
    }
    finalize_one(out, 4 * t + 0, (float)c0);
    finalize_one(out, 4 * t + 1, (float)c1);
    finalize_one(out, 4 * t + 2, (float)c2);
    finalize_one(out, 4 * t + 3, (float)c3);
}

extern "C" void kernel_launch(void* const* d_in, const int* in_sizes, int n_in,
                              void* d_out, int out_size, void* d_ws, size_t ws_size,
                              hipStream_t stream) {
    const int*   src     = (const int*)  d_in[0];
    const int*   dst     = (const int*)  d_in[1];
    const float* energy  = (const float*)d_in[2];
    const int*   layer   = (const int*)  d_in[3];
    const float* eta_src = (const float*)d_in[4];
    const float* phi_src = (const float*)d_in[5];
    const float* eta_dst = (const float*)d_in[6];
    const float* phi_dst = (const float*)d_in[7];
    float* out = (float*)d_out;

    pack_kernel<<<(N_OUT + 255) / 256, 256, 0, stream>>>(
        energy, layer, eta_src, phi_src, eta_dst, phi_dst, out);

    edge_kernel<<<EBLK, ETPB, 0, stream>>>(
        (const vint4*)src, (const vint4*)dst, out);

    finalize_kernel<<<(N_DST / 4 + 255) / 256, 256, 0, stream>>>(out);
}